// Round 5
// baseline (467.422 us; speedup 1.0000x reference)
//
#include <hip/hip_runtime.h>
#include <math.h>

// B=2, S=2048, D=1024, F=4096, H=16, hd=64
#define BB 2
#define SS 2048
#define DD 1024
#define FF 4096
#define HH 16
#define MM (BB * SS)  // 4096

typedef __attribute__((ext_vector_type(8))) short short8v;
typedef __attribute__((ext_vector_type(4))) float float4v;
typedef __attribute__((ext_vector_type(4))) unsigned short ushort4v;
typedef __attribute__((ext_vector_type(8))) unsigned short ushort8v;
typedef unsigned short u16;
typedef unsigned int u32;

#define MFMA16(A_, B_, C_) __builtin_amdgcn_mfma_f32_16x16x32_bf16((A_), (B_), (C_), 0, 0, 0)

__device__ __forceinline__ u16 f2bf(float f) {  // RNE float->bf16
    u32 u = __float_as_uint(f);
    u += 0x7FFF + ((u >> 16) & 1);
    return (u16)(u >> 16);
}

__device__ __forceinline__ void async16(void* lds, const void* g) {
    __builtin_amdgcn_global_load_lds(
        (const __attribute__((address_space(1))) u32*)g,
        (__attribute__((address_space(3))) u32*)lds, 16, 0, 0);
}

__device__ __forceinline__ float gelu_f(float x) {
    // 0.5x(1+tanh(0.79788456(x+0.044715x^3))), tanh via exp2
    float u = 0.7978845608028654f * x * (1.0f + 0.044715f * x * x);
    float e = exp2f(u * 2.8853900817779268f);   // e^{2u}
    float th = 1.0f - 2.0f / (e + 1.0f);
    return 0.5f * x * (1.0f + th);
}

// ---------------------------------------------------------------------------
// srmsnorm: f32 in -> bf16 out. One block per row, 256 thr, float4/thread.
// ---------------------------------------------------------------------------
__global__ __launch_bounds__(256) void srmsnorm_bf16(const float* __restrict__ in,
                                                     u16* __restrict__ out) {
    const int row = blockIdx.x, t = threadIdx.x;
    float4 a = reinterpret_cast<const float4*>(in + (size_t)row * DD)[t];
    float ss = a.x * a.x + a.y * a.y + a.z * a.z + a.w * a.w;
#pragma unroll
    for (int off = 32; off > 0; off >>= 1) ss += __shfl_xor(ss, off);
    __shared__ float red[4];
    if ((t & 63) == 0) red[t >> 6] = ss;
    __syncthreads();
    float tot = red[0] + red[1] + red[2] + red[3];
    float sc = 32.0f / fmaxf(sqrtf(tot), 1e-12f);   // sqrt(1024)=32
    ushort4v ov;
    ov[0] = f2bf(a.x * sc); ov[1] = f2bf(a.y * sc);
    ov[2] = f2bf(a.z * sc); ov[3] = f2bf(a.w * sc);
    *(ushort4v*)(out + (size_t)row * DD + t * 4) = ov;
}

// ---------------------------------------------------------------------------
// weight transpose+cast: in f32 [K][N] -> out bf16 [N][K]. 64x64 tiles.
// ---------------------------------------------------------------------------
__global__ __launch_bounds__(256) void wtrans(const float* __restrict__ in,
                                              u16* __restrict__ out, int K, int N) {
    __shared__ float T[64][65];
    const int t = threadIdx.x;
    const int n0 = blockIdx.x * 64, k0 = blockIdx.y * 64;
#pragma unroll
    for (int i = 0; i < 4; ++i) {
        int r = i * 16 + (t >> 4), c4 = (t & 15) * 4;
        float4 v = *reinterpret_cast<const float4*>(in + (size_t)(k0 + r) * N + n0 + c4);
        T[r][c4 + 0] = v.x; T[r][c4 + 1] = v.y; T[r][c4 + 2] = v.z; T[r][c4 + 3] = v.w;
    }
    __syncthreads();
#pragma unroll
    for (int i = 0; i < 4; ++i) {
        int r = i * 16 + (t >> 4), c4 = (t & 15) * 4;
        ushort4v ov;
#pragma unroll
        for (int j = 0; j < 4; ++j) ov[j] = f2bf(T[c4 + j][r]);
        *(ushort4v*)(out + (size_t)(n0 + r) * K + k0 + c4) = ov;
    }
}

// ---------------------------------------------------------------------------
// V transpose: vb bf16 [B*S][D] -> vt bf16 [B*H][64][S]. pad 88 keeps 16B
// stores aligned.
// ---------------------------------------------------------------------------
__global__ __launch_bounds__(256) void vtrans(const u16* __restrict__ vb,
                                              u16* __restrict__ vt) {
    __shared__ u16 T[64][88];
    const int t = threadIdx.x;
    const int s0 = blockIdx.x * 64, bh = blockIdx.y;
    const int b = bh >> 4, h = bh & 15;
#pragma unroll
    for (int i = 0; i < 2; ++i) {
        int r = i * 32 + (t >> 3), c8 = (t & 7) * 8;
        *(ushort8v*)&T[r][c8] =
            *(const ushort8v*)(vb + (size_t)(b * SS + s0 + r) * DD + h * 64 + c8);
    }
    __syncthreads();
#pragma unroll
    for (int i = 0; i < 2; ++i) {
        int d = i * 32 + (t >> 3), s8 = (t & 7) * 8;
        ushort8v ov;
#pragma unroll
        for (int j = 0; j < 8; ++j) ov[j] = T[s8 + j][d];
        *(ushort8v*)(vt + ((size_t)bh * 64 + d) * SS + s0 + s8) = ov;
    }
}

// ---------------------------------------------------------------------------
// bf16 MFMA GEMM (m97 structure): C[M,N] = A[M,K] * Bt[N,K]^T
// BK=32, 256 thr = 4 waves (2x2), global_load_lds width 16, 2 barriers/K-step.
// EPI 0: bf16 out. EPI 1: f32 out = acc + Res. EPI 2: bf16 out = gelu(acc).
// EPI 3: fused-QKV scatter: Cout = base of 3 contiguous [M][1024] bf16 bufs,
//        segment = col0>>10 (BN=128 divides 1024 -> block stays in one seg).
// ---------------------------------------------------------------------------
template <int BM, int BN, int EPI>
__global__ __launch_bounds__(256) void gemm_bf16(const u16* __restrict__ A,
                                                 const u16* __restrict__ Bt,
                                                 const float* __restrict__ Res,
                                                 void* __restrict__ Cout,
                                                 int M, int N, int K) {
    __shared__ u16 As[BM * 32];
    __shared__ u16 Bs[BN * 32];
    constexpr int FM = BM / 32, FN = BN / 32;
    const int t = threadIdx.x;
    const int w = t >> 6, lane = t & 63;
    const int g = lane >> 4, c = lane & 15;
    const int wr = w >> 1, wc = w & 1;
    const int bm = blockIdx.y * BM, bn = blockIdx.x * BN;
    const int arow = t >> 2, au = (t & 3) * 8;   // staging: 16B per thread

    float4v acc[FM][FN] = {};
    for (int k0 = 0; k0 < K; k0 += 32) {
        __syncthreads();   // prev iteration's LDS reads done
#pragma unroll
        for (int p = 0; p < BM / 64; ++p)
            async16(&As[(p * 64 + arow) * 32 + au],
                    A + (size_t)(bm + p * 64 + arow) * K + k0 + au);
#pragma unroll
        for (int p = 0; p < BN / 64; ++p)
            async16(&Bs[(p * 64 + arow) * 32 + au],
                    Bt + (size_t)(bn + p * 64 + arow) * K + k0 + au);
        __syncthreads();   // drains vmcnt -> LDS visible
        short8v af[FM], bf[FN];
#pragma unroll
        for (int mi = 0; mi < FM; ++mi)
            af[mi] = *(const short8v*)&As[(wr * (BM / 2) + mi * 16 + c) * 32 + g * 8];
#pragma unroll
        for (int ni = 0; ni < FN; ++ni)
            bf[ni] = *(const short8v*)&Bs[(wc * (BN / 2) + ni * 16 + c) * 32 + g * 8];
#pragma unroll
        for (int mi = 0; mi < FM; ++mi)
#pragma unroll
            for (int ni = 0; ni < FN; ++ni)
                acc[mi][ni] = MFMA16(af[mi], bf[ni], acc[mi][ni]);
    }
    const int row0 = bm + wr * (BM / 2), col0 = bn + wc * (BN / 2);
    if (EPI == 3) {
        const int seg = col0 >> 10, c0 = col0 & 1023;
        u16* dst = (u16*)Cout + (size_t)seg * ((size_t)MM * 1024);
#pragma unroll
        for (int mi = 0; mi < FM; ++mi)
#pragma unroll
            for (int r = 0; r < 4; ++r) {
                const size_t rw = (size_t)(row0 + mi * 16 + 4 * g + r) * 1024;
#pragma unroll
                for (int ni = 0; ni < FN; ++ni)
                    dst[rw + c0 + ni * 16 + c] = f2bf(acc[mi][ni][r]);
            }
        return;
    }
#pragma unroll
    for (int mi = 0; mi < FM; ++mi)
#pragma unroll
        for (int r = 0; r < 4; ++r) {
            const size_t rw = (size_t)(row0 + mi * 16 + 4 * g + r) * N;
#pragma unroll
            for (int ni = 0; ni < FN; ++ni) {
                const size_t off = rw + col0 + ni * 16 + c;
                float v = acc[mi][ni][r];
                if (EPI == 0)      ((u16*)Cout)[off] = f2bf(v);
                else if (EPI == 1) ((float*)Cout)[off] = v + Res[off];
                else               ((u16*)Cout)[off] = f2bf(gelu_f(v));
            }
        }
}

// ---------------------------------------------------------------------------
// Causal flash attention, bf16 MFMA. One 64-thread block = one wave = one
// 16-q-row unit. 4096 blocks, LPT (heaviest ktmax dispatched first) -> high
// occupancy + balanced. K/V fragments from global (L2-resident); P
// lane-transpose via tiny padded LDS (same-wave DS ordering, no barrier).
// ---------------------------------------------------------------------------
__global__ __launch_bounds__(64) void attn_mfma(const u16* __restrict__ Qb,
                                                const u16* __restrict__ Kb,
                                                const u16* __restrict__ Vt,
                                                u16* __restrict__ Ao) {
    __shared__ u16 Pl[16][88];
    const int lane = threadIdx.x;
    const int g = lane >> 4, c = lane & 15;
    const int bid = blockIdx.x;
    const int bh = bid & 31;                 // 32 (b,h) pairs
    const int u = 127 - (bid >> 5);          // 16-row unit, heavy first
    const int b = bh >> 4, h = bh & 15;
    const int qrow0 = u * 16;
    const int ktmax = qrow0 >> 6;
    const size_t qkbase = (size_t)b * SS * DD + h * 64;
    const size_t vbase = (size_t)bh * 64 * SS;
    constexpr float SC = 0.18033688011112042f;  // 0.125 * log2(e)

    short8v qf[2];
#pragma unroll
    for (int kh = 0; kh < 2; ++kh)
        qf[kh] = *(const short8v*)(Qb + qkbase +
                     (size_t)(qrow0 + c) * DD + kh * 32 + g * 8);

    float4v o[4] = {};
    float m_run[4] = {-1e30f, -1e30f, -1e30f, -1e30f};
    float l_run[4] = {0.0f, 0.0f, 0.0f, 0.0f};

    for (int kt = 0; kt <= ktmax; ++kt) {
        // ---- scores S = Q K^T ----
        short8v kf[4][2];
#pragma unroll
        for (int nb = 0; nb < 4; ++nb)
#pragma unroll
            for (int kh = 0; kh < 2; ++kh)
                kf[nb][kh] = *(const short8v*)(Kb + qkbase +
                                 (size_t)(kt * 64 + nb * 16 + c) * DD + kh * 32 + g * 8);
        float4v sa[4] = {};
#pragma unroll
        for (int nb = 0; nb < 4; ++nb)
#pragma unroll
            for (int kh = 0; kh < 2; ++kh)
                sa[nb] = MFMA16(qf[kh], kf[nb][kh], sa[nb]);

        const bool diag = (kt == ktmax);
#pragma unroll
        for (int nb = 0; nb < 4; ++nb)
#pragma unroll
            for (int r = 0; r < 4; ++r) {
                float v = sa[nb][r] * SC;
                if (diag && (kt * 64 + nb * 16 + c > qrow0 + 4 * g + r))
                    v = -3e38f;
                sa[nb][r] = v;
            }

        // ---- online softmax (row = qrow0+4g+r, spread over 16 c-lanes) ----
        float corr[4];
#pragma unroll
        for (int r = 0; r < 4; ++r) {
            float m0 = fmaxf(fmaxf(sa[0][r], sa[1][r]), fmaxf(sa[2][r], sa[3][r]));
            m0 = fmaxf(m0, __shfl_xor(m0, 1));
            m0 = fmaxf(m0, __shfl_xor(m0, 2));
            m0 = fmaxf(m0, __shfl_xor(m0, 4));
            m0 = fmaxf(m0, __shfl_xor(m0, 8));
            float mn = fmaxf(m_run[r], m0);
            corr[r] = exp2f(m_run[r] - mn);
            m_run[r] = mn;
        }
#pragma unroll
        for (int nb = 0; nb < 4; ++nb)
#pragma unroll
            for (int r = 0; r < 4; ++r)
                sa[nb][r] = exp2f(sa[nb][r] - m_run[r]);
#pragma unroll
        for (int r = 0; r < 4; ++r) {
            float s_ = sa[0][r] + sa[1][r] + sa[2][r] + sa[3][r];
            s_ += __shfl_xor(s_, 1); s_ += __shfl_xor(s_, 2);
            s_ += __shfl_xor(s_, 4); s_ += __shfl_xor(s_, 8);
            l_run[r] = l_run[r] * corr[r] + s_;
        }
        float4v cv; cv[0] = corr[0]; cv[1] = corr[1]; cv[2] = corr[2]; cv[3] = corr[3];
#pragma unroll
        for (int nb = 0; nb < 4; ++nb) o[nb] *= cv;

        // P -> bf16 -> LDS (lane transpose for A-fragment); same-wave DS
        // ordering makes write->read safe without a barrier.
#pragma unroll
        for (int nb = 0; nb < 4; ++nb)
#pragma unroll
            for (int r = 0; r < 4; ++r)
                Pl[4 * g + r][nb * 16 + c] = f2bf(sa[nb][r]);

        // ---- O += P V ----
        short8v pa[2];
#pragma unroll
        for (int kh = 0; kh < 2; ++kh)
            pa[kh] = *(const short8v*)&Pl[c][kh * 32 + g * 8];
        short8v vf[4][2];
#pragma unroll
        for (int nb = 0; nb < 4; ++nb)
#pragma unroll
            for (int kh = 0; kh < 2; ++kh)
                vf[nb][kh] = *(const short8v*)(Vt + vbase +
                                 (size_t)(nb * 16 + c) * SS + kt * 64 + kh * 32 + g * 8);
#pragma unroll
        for (int nb = 0; nb < 4; ++nb)
#pragma unroll
            for (int kh = 0; kh < 2; ++kh)
                o[nb] = MFMA16(pa[kh], vf[nb][kh], o[nb]);
    }

    // epilogue: O / l -> bf16
    float inv[4];
#pragma unroll
    for (int r = 0; r < 4; ++r) inv[r] = 1.0f / l_run[r];
#pragma unroll
    for (int nb = 0; nb < 4; ++nb)
#pragma unroll
        for (int r = 0; r < 4; ++r)
            Ao[qkbase + (size_t)(qrow0 + 4 * g + r) * DD + nb * 16 + c] =
                f2bf(o[nb][r] * inv[r]);
}

// ---------------------------------------------------------------------------
// launch: h = x + attn(srmsnorm(x)); out = h + gelu(srmsnorm(h)@w_in)@w_out
// ws layout (MB): 0 wq_t | 2 wk_t | 4 wv_t (contiguous = fused [3072][1024])
//  | 6 wo_t | 8 wi_t | 16 wo2_t | 24 xn | 32 qb | 40 kb | 48 vb (contiguous)
//  | 56 vt | 64 ao | 72 hn | 80 g(32MB) = 112MB
// ---------------------------------------------------------------------------
extern "C" void kernel_launch(void* const* d_in, const int* in_sizes, int n_in,
                              void* d_out, int out_size, void* d_ws, size_t ws_size,
                              hipStream_t stream) {
    const float* x     = (const float*)d_in[0];
    const float* wq    = (const float*)d_in[1];
    const float* wk    = (const float*)d_in[2];
    const float* wv    = (const float*)d_in[3];
    const float* wo    = (const float*)d_in[4];
    const float* w_in  = (const float*)d_in[5];
    const float* w_out = (const float*)d_in[6];
    float* out = (float*)d_out;
    char* ws = (char*)d_ws;
    const size_t MB = 1024 * 1024;
    u16* wq_t  = (u16*)(ws + 0 * MB);   // [3072][1024] fused (wq|wk|wv)
    u16* wk_t  = (u16*)(ws + 2 * MB);
    u16* wv_t  = (u16*)(ws + 4 * MB);
    u16* wo_t  = (u16*)(ws + 6 * MB);
    u16* wi_t  = (u16*)(ws + 8 * MB);
    u16* wo2_t = (u16*)(ws + 16 * MB);
    u16* xn    = (u16*)(ws + 24 * MB);
    u16* qb    = (u16*)(ws + 32 * MB);  // q|k|v contiguous [3][4096][1024]
    u16* vb    = (u16*)(ws + 48 * MB);
    u16* vt    = (u16*)(ws + 56 * MB);
    u16* ao    = (u16*)(ws + 64 * MB);
    u16* hn    = (u16*)(ws + 72 * MB);
    u16* gbuf  = (u16*)(ws + 80 * MB);

    dim3 blk(256);
    // weights -> bf16 transposed [N][K]
    wtrans<<<dim3(DD / 64, DD / 64), blk, 0, stream>>>(wq, wq_t, DD, DD);
    wtrans<<<dim3(DD / 64, DD / 64), blk, 0, stream>>>(wk, wk_t, DD, DD);
    wtrans<<<dim3(DD / 64, DD / 64), blk, 0, stream>>>(wv, wv_t, DD, DD);
    wtrans<<<dim3(DD / 64, DD / 64), blk, 0, stream>>>(wo, wo_t, DD, DD);
    wtrans<<<dim3(FF / 64, DD / 64), blk, 0, stream>>>(w_in, wi_t, DD, FF);
    wtrans<<<dim3(DD / 64, FF / 64), blk, 0, stream>>>(w_out, wo2_t, FF, DD);

    srmsnorm_bf16<<<MM, blk, 0, stream>>>(x, xn);
    // fused QKV: N=3072, epilogue scatters into qb/kb/vb
    gemm_bf16<128, 128, 3><<<dim3(3072 / 128, MM / 128), blk, 0, stream>>>(
        xn, wq_t, nullptr, qb, MM, 3072, DD);
    vtrans<<<dim3(SS / 64, BB * HH), blk, 0, stream>>>(vb, vt);
    attn_mfma<<<dim3(32 * 128), dim3(64), 0, stream>>>(qb, qb + (size_t)MM * 1024, vt, ao);
    gemm_bf16<128, 128, 1><<<dim3(DD / 128, MM / 128), blk, 0, stream>>>(ao, wo_t, x, out, MM, DD, DD); // h
    srmsnorm_bf16<<<MM, blk, 0, stream>>>(out, hn);
    gemm_bf16<128, 128, 2><<<dim3(FF / 128, MM / 128), blk, 0, stream>>>(hn, wi_t, nullptr, gbuf, MM, FF, DD);
    gemm_bf16<128, 128, 1><<<dim3(DD / 128, MM / 128), blk, 0, stream>>>(gbuf, wo2_t, out, out, MM, DD, FF); // h+ff
}

// Round 6
// 430.239 us; speedup vs baseline: 1.0864x; 1.0864x over previous
//
#include <hip/hip_runtime.h>
#include <math.h>

// B=2, S=2048, D=1024, F=4096, H=16, hd=64
#define BB 2
#define SS 2048
#define DD 1024
#define FF 4096
#define HH 16
#define MM (BB * SS)  // 4096

typedef __attribute__((ext_vector_type(8))) short short8v;
typedef __attribute__((ext_vector_type(4))) float float4v;
typedef __attribute__((ext_vector_type(4))) unsigned short ushort4v;
typedef __attribute__((ext_vector_type(8))) unsigned short ushort8v;
typedef unsigned short u16;
typedef unsigned int u32;

#define MFMA16(A_, B_, C_) __builtin_amdgcn_mfma_f32_16x16x32_bf16((A_), (B_), (C_), 0, 0, 0)

__device__ __forceinline__ u16 f2bf(float f) {  // RNE float->bf16
    u32 u = __float_as_uint(f);
    u += 0x7FFF + ((u >> 16) & 1);
    return (u16)(u >> 16);
}

__device__ __forceinline__ void async16(void* lds, const void* g) {
    __builtin_amdgcn_global_load_lds(
        (const __attribute__((address_space(1))) u32*)g,
        (__attribute__((address_space(3))) u32*)lds, 16, 0, 0);
}

__device__ __forceinline__ float gelu_f(float x) {
    // 0.5x(1+tanh(0.79788456(x+0.044715x^3))), tanh via exp2
    float u = 0.7978845608028654f * x * (1.0f + 0.044715f * x * x);
    float e = exp2f(u * 2.8853900817779268f);   // e^{2u}
    float th = 1.0f - 2.0f / (e + 1.0f);
    return 0.5f * x * (1.0f + th);
}

// ---------------------------------------------------------------------------
// srmsnorm: f32 in -> bf16 out. One block per row, 256 thr, float4/thread.
// ---------------------------------------------------------------------------
__global__ __launch_bounds__(256) void srmsnorm_bf16(const float* __restrict__ in,
                                                     u16* __restrict__ out) {
    const int row = blockIdx.x, t = threadIdx.x;
    float4 a = reinterpret_cast<const float4*>(in + (size_t)row * DD)[t];
    float ss = a.x * a.x + a.y * a.y + a.z * a.z + a.w * a.w;
#pragma unroll
    for (int off = 32; off > 0; off >>= 1) ss += __shfl_xor(ss, off);
    __shared__ float red[4];
    if ((t & 63) == 0) red[t >> 6] = ss;
    __syncthreads();
    float tot = red[0] + red[1] + red[2] + red[3];
    float sc = 32.0f / fmaxf(sqrtf(tot), 1e-12f);   // sqrt(1024)=32
    ushort4v ov;
    ov[0] = f2bf(a.x * sc); ov[1] = f2bf(a.y * sc);
    ov[2] = f2bf(a.z * sc); ov[3] = f2bf(a.w * sc);
    *(ushort4v*)(out + (size_t)row * DD + t * 4) = ov;
}

// ---------------------------------------------------------------------------
// ALL weight transposes fused into one launch. in f32 [K][N] -> out bf16
// [N][K], 64x64 tiles. Block-id decode:
//   [0,1024):   wq/wk/wv/wo (256 blocks each, 16x16)
//   [1024,2048): w_in  (K=1024,N=4096 -> 64 nb x 16 kb)
//   [2048,3072): w_out (K=4096,N=1024 -> 16 nb x 64 kb)
// ---------------------------------------------------------------------------
__device__ __forceinline__ void trans_tile(const float* __restrict__ in,
                                           u16* __restrict__ out, int K, int N,
                                           int n0, int k0, int t, float (*T)[65]) {
#pragma unroll
    for (int i = 0; i < 4; ++i) {
        int r = i * 16 + (t >> 4), c4 = (t & 15) * 4;
        float4 v = *reinterpret_cast<const float4*>(in + (size_t)(k0 + r) * N + n0 + c4);
        T[r][c4 + 0] = v.x; T[r][c4 + 1] = v.y; T[r][c4 + 2] = v.z; T[r][c4 + 3] = v.w;
    }
    __syncthreads();
#pragma unroll
    for (int i = 0; i < 4; ++i) {
        int r = i * 16 + (t >> 4), c4 = (t & 15) * 4;
        ushort4v ov;
#pragma unroll
        for (int j = 0; j < 4; ++j) ov[j] = f2bf(T[c4 + j][r]);
        *(ushort4v*)(out + (size_t)(n0 + r) * K + k0 + c4) = ov;
    }
}

__global__ __launch_bounds__(256) void wtrans_all(const float* __restrict__ wq,
                                                  const float* __restrict__ wk,
                                                  const float* __restrict__ wv,
                                                  const float* __restrict__ wo,
                                                  const float* __restrict__ wi,
                                                  const float* __restrict__ wo2,
                                                  char* __restrict__ ws) {
    __shared__ float T[64][65];
    const int t = threadIdx.x;
    const size_t MB = 1024 * 1024;
    int id = blockIdx.x;
    if (id < 1024) {
        const int which = id >> 8, l = id & 255;
        const float* in = which == 0 ? wq : which == 1 ? wk : which == 2 ? wv : wo;
        u16* out = (u16*)(ws + (size_t)which * 2 * MB);   // 0,2,4,6 MB
        trans_tile(in, out, 1024, 1024, (l & 15) * 64, (l >> 4) * 64, t, T);
    } else if (id < 2048) {
        const int l = id - 1024;
        trans_tile(wi, (u16*)(ws + 8 * MB), 1024, 4096,
                   (l & 63) * 64, (l >> 6) * 64, t, T);
    } else {
        const int l = id - 2048;
        trans_tile(wo2, (u16*)(ws + 16 * MB), 4096, 1024,
                   (l & 15) * 64, (l >> 4) * 64, t, T);
    }
}

// ---------------------------------------------------------------------------
// V transpose: vb bf16 [B*S][D] -> vt bf16 [B*H][64][S]. pad 88 keeps 16B
// stores aligned.
// ---------------------------------------------------------------------------
__global__ __launch_bounds__(256) void vtrans(const u16* __restrict__ vb,
                                              u16* __restrict__ vt) {
    __shared__ u16 T[64][88];
    const int t = threadIdx.x;
    const int s0 = blockIdx.x * 64, bh = blockIdx.y;
    const int b = bh >> 4, h = bh & 15;
#pragma unroll
    for (int i = 0; i < 2; ++i) {
        int r = i * 32 + (t >> 3), c8 = (t & 7) * 8;
        *(ushort8v*)&T[r][c8] =
            *(const ushort8v*)(vb + (size_t)(b * SS + s0 + r) * DD + h * 64 + c8);
    }
    __syncthreads();
#pragma unroll
    for (int i = 0; i < 2; ++i) {
        int d = i * 32 + (t >> 3), s8 = (t & 7) * 8;
        ushort8v ov;
#pragma unroll
        for (int j = 0; j < 8; ++j) ov[j] = T[s8 + j][d];
        *(ushort8v*)(vt + ((size_t)bh * 64 + d) * SS + s0 + s8) = ov;
    }
}

// ---------------------------------------------------------------------------
// bf16 MFMA GEMM (m97 structure): C[M,N] = A[M,K] * Bt[N,K]^T
// BK=32, 256 thr = 4 waves (2x2), global_load_lds width 16, 2 barriers/K-step.
// EPI 0: bf16 out. EPI 1: f32 out = acc + Res. EPI 2: bf16 out = gelu(acc).
// EPI 3: fused-QKV scatter into 3 contiguous [M][1024] bf16 bufs.
// ---------------------------------------------------------------------------
template <int BM, int BN, int EPI>
__global__ __launch_bounds__(256) void gemm_bf16(const u16* __restrict__ A,
                                                 const u16* __restrict__ Bt,
                                                 const float* __restrict__ Res,
                                                 void* __restrict__ Cout,
                                                 int M, int N, int K) {
    __shared__ u16 As[BM * 32];
    __shared__ u16 Bs[BN * 32];
    constexpr int FM = BM / 32, FN = BN / 32;
    const int t = threadIdx.x;
    const int w = t >> 6, lane = t & 63;
    const int g = lane >> 4, c = lane & 15;
    const int wr = w >> 1, wc = w & 1;
    const int bm = blockIdx.y * BM, bn = blockIdx.x * BN;
    const int arow = t >> 2, au = (t & 3) * 8;   // staging: 16B per thread

    float4v acc[FM][FN] = {};
    for (int k0 = 0; k0 < K; k0 += 32) {
        __syncthreads();   // prev iteration's LDS reads done
#pragma unroll
        for (int p = 0; p < BM / 64; ++p)
            async16(&As[(p * 64 + arow) * 32 + au],
                    A + (size_t)(bm + p * 64 + arow) * K + k0 + au);
#pragma unroll
        for (int p = 0; p < BN / 64; ++p)
            async16(&Bs[(p * 64 + arow) * 32 + au],
                    Bt + (size_t)(bn + p * 64 + arow) * K + k0 + au);
        __syncthreads();   // drains vmcnt -> LDS visible
        short8v af[FM], bf[FN];
#pragma unroll
        for (int mi = 0; mi < FM; ++mi)
            af[mi] = *(const short8v*)&As[(wr * (BM / 2) + mi * 16 + c) * 32 + g * 8];
#pragma unroll
        for (int ni = 0; ni < FN; ++ni)
            bf[ni] = *(const short8v*)&Bs[(wc * (BN / 2) + ni * 16 + c) * 32 + g * 8];
#pragma unroll
        for (int mi = 0; mi < FM; ++mi)
#pragma unroll
            for (int ni = 0; ni < FN; ++ni)
                acc[mi][ni] = MFMA16(af[mi], bf[ni], acc[mi][ni]);
    }
    const int row0 = bm + wr * (BM / 2), col0 = bn + wc * (BN / 2);
    if (EPI == 3) {
        const int seg = col0 >> 10, c0 = col0 & 1023;
        u16* dst = (u16*)Cout + (size_t)seg * ((size_t)MM * 1024);
#pragma unroll
        for (int mi = 0; mi < FM; ++mi)
#pragma unroll
            for (int r = 0; r < 4; ++r) {
                const size_t rw = (size_t)(row0 + mi * 16 + 4 * g + r) * 1024;
#pragma unroll
                for (int ni = 0; ni < FN; ++ni)
                    dst[rw + c0 + ni * 16 + c] = f2bf(acc[mi][ni][r]);
            }
        return;
    }
#pragma unroll
    for (int mi = 0; mi < FM; ++mi)
#pragma unroll
        for (int r = 0; r < 4; ++r) {
            const size_t rw = (size_t)(row0 + mi * 16 + 4 * g + r) * N;
#pragma unroll
            for (int ni = 0; ni < FN; ++ni) {
                const size_t off = rw + col0 + ni * 16 + c;
                float v = acc[mi][ni][r];
                if (EPI == 0)      ((u16*)Cout)[off] = f2bf(v);
                else if (EPI == 1) ((float*)Cout)[off] = v + Res[off];
                else               ((u16*)Cout)[off] = f2bf(gelu_f(v));
            }
        }
}

// ---------------------------------------------------------------------------
// Causal flash attention, bf16 MFMA. One 64-thread block = one wave = one
// 32-q-row unit (round-4 per-wave intensity, round-5 occupancy). 2048 blocks,
// LPT (heavy units first). K/V fragments from global (L2-resident); P
// lane-transpose via tiny padded LDS (same-wave DS ordering, no barrier).
// s_setprio(1) around MFMA clusters (m191: helps independent 1-wave blocks).
// ---------------------------------------------------------------------------
__global__ __launch_bounds__(64) void attn_mfma(const u16* __restrict__ Qb,
                                                const u16* __restrict__ Kb,
                                                const u16* __restrict__ Vt,
                                                u16* __restrict__ Ao) {
    __shared__ u16 Pl[2][16][88];
    const int lane = threadIdx.x;
    const int g = lane >> 4, c = lane & 15;
    const int bid = blockIdx.x;
    const int bh = bid & 31;                 // 32 (b,h) pairs
    const int u = 63 - (bid >> 5);           // 32-row unit, heavy first
    const int b = bh >> 4, h = bh & 15;
    const int qrow0 = u * 32;
    const int ktmax = qrow0 >> 6;            // qrow0 multiple of 32
    const size_t qkbase = (size_t)b * SS * DD + h * 64;
    const size_t vbase = (size_t)bh * 64 * SS;
    constexpr float SC = 0.18033688011112042f;  // 0.125 * log2(e)

    short8v qf[2][2];
#pragma unroll
    for (int rb = 0; rb < 2; ++rb)
#pragma unroll
        for (int kh = 0; kh < 2; ++kh)
            qf[rb][kh] = *(const short8v*)(Qb + qkbase +
                             (size_t)(qrow0 + rb * 16 + c) * DD + kh * 32 + g * 8);

    float4v o[2][4] = {};
    float m_run[2][4], l_run[2][4];
#pragma unroll
    for (int rb = 0; rb < 2; ++rb)
#pragma unroll
        for (int r = 0; r < 4; ++r) { m_run[rb][r] = -1e30f; l_run[rb][r] = 0.0f; }

    for (int kt = 0; kt <= ktmax; ++kt) {
        // ---- scores S = Q K^T ----
        short8v kf[4][2];
#pragma unroll
        for (int nb = 0; nb < 4; ++nb)
#pragma unroll
            for (int kh = 0; kh < 2; ++kh)
                kf[nb][kh] = *(const short8v*)(Kb + qkbase +
                                 (size_t)(kt * 64 + nb * 16 + c) * DD + kh * 32 + g * 8);
        float4v sa[2][4] = {};
        __builtin_amdgcn_s_setprio(1);
#pragma unroll
        for (int nb = 0; nb < 4; ++nb)
#pragma unroll
            for (int kh = 0; kh < 2; ++kh)
#pragma unroll
                for (int rb = 0; rb < 2; ++rb)
                    sa[rb][nb] = MFMA16(qf[rb][kh], kf[nb][kh], sa[rb][nb]);
        __builtin_amdgcn_s_setprio(0);

        const bool diag = (kt == ktmax);
#pragma unroll
        for (int rb = 0; rb < 2; ++rb)
#pragma unroll
            for (int nb = 0; nb < 4; ++nb)
#pragma unroll
                for (int r = 0; r < 4; ++r) {
                    float v = sa[rb][nb][r] * SC;
                    if (diag && (kt * 64 + nb * 16 + c > qrow0 + rb * 16 + 4 * g + r))
                        v = -3e38f;
                    sa[rb][nb][r] = v;
                }

        // ---- online softmax (rows live in 16-lane groups) ----
#pragma unroll
        for (int rb = 0; rb < 2; ++rb) {
            float corr[4];
#pragma unroll
            for (int r = 0; r < 4; ++r) {
                float m0 = fmaxf(fmaxf(sa[rb][0][r], sa[rb][1][r]),
                                 fmaxf(sa[rb][2][r], sa[rb][3][r]));
                m0 = fmaxf(m0, __shfl_xor(m0, 1));
                m0 = fmaxf(m0, __shfl_xor(m0, 2));
                m0 = fmaxf(m0, __shfl_xor(m0, 4));
                m0 = fmaxf(m0, __shfl_xor(m0, 8));
                float mn = fmaxf(m_run[rb][r], m0);
                corr[r] = exp2f(m_run[rb][r] - mn);
                m_run[rb][r] = mn;
            }
#pragma unroll
            for (int nb = 0; nb < 4; ++nb)
#pragma unroll
                for (int r = 0; r < 4; ++r)
                    sa[rb][nb][r] = exp2f(sa[rb][nb][r] - m_run[rb][r]);
#pragma unroll
            for (int r = 0; r < 4; ++r) {
                float s_ = sa[rb][0][r] + sa[rb][1][r] + sa[rb][2][r] + sa[rb][3][r];
                s_ += __shfl_xor(s_, 1); s_ += __shfl_xor(s_, 2);
                s_ += __shfl_xor(s_, 4); s_ += __shfl_xor(s_, 8);
                l_run[rb][r] = l_run[rb][r] * corr[r] + s_;
            }
            float4v cv; cv[0] = corr[0]; cv[1] = corr[1]; cv[2] = corr[2]; cv[3] = corr[3];
#pragma unroll
            for (int nb = 0; nb < 4; ++nb) o[rb][nb] *= cv;
            // P -> bf16 -> LDS (lane transpose); same-wave DS ordering, no barrier
#pragma unroll
            for (int nb = 0; nb < 4; ++nb)
#pragma unroll
                for (int r = 0; r < 4; ++r)
                    Pl[rb][4 * g + r][nb * 16 + c] = f2bf(sa[rb][nb][r]);
        }

        // ---- O += P V ----
        short8v pa[2][2];
#pragma unroll
        for (int rb = 0; rb < 2; ++rb)
#pragma unroll
            for (int kh = 0; kh < 2; ++kh)
                pa[rb][kh] = *(const short8v*)&Pl[rb][c][kh * 32 + g * 8];
        short8v vf[4][2];
#pragma unroll
        for (int nb = 0; nb < 4; ++nb)
#pragma unroll
            for (int kh = 0; kh < 2; ++kh)
                vf[nb][kh] = *(const short8v*)(Vt + vbase +
                                 (size_t)(nb * 16 + c) * SS + kt * 64 + kh * 32 + g * 8);
        __builtin_amdgcn_s_setprio(1);
#pragma unroll
        for (int nb = 0; nb < 4; ++nb)
#pragma unroll
            for (int kh = 0; kh < 2; ++kh)
#pragma unroll
                for (int rb = 0; rb < 2; ++rb)
                    o[rb][nb] = MFMA16(pa[rb][kh], vf[nb][kh], o[rb][nb]);
        __builtin_amdgcn_s_setprio(0);
    }

    // epilogue: O / l -> bf16
#pragma unroll
    for (int rb = 0; rb < 2; ++rb) {
        float inv[4];
#pragma unroll
        for (int r = 0; r < 4; ++r) inv[r] = 1.0f / l_run[rb][r];
#pragma unroll
        for (int nb = 0; nb < 4; ++nb)
#pragma unroll
            for (int r = 0; r < 4; ++r)
                Ao[qkbase + (size_t)(qrow0 + rb * 16 + 4 * g + r) * DD + nb * 16 + c] =
                    f2bf(o[rb][nb][r] * inv[r]);
    }
}

// ---------------------------------------------------------------------------
// launch: h = x + attn(srmsnorm(x)); out = h + gelu(srmsnorm(h)@w_in)@w_out
// ws layout (MB): 0 wq_t | 2 wk_t | 4 wv_t (contiguous fused [3072][1024])
//  | 6 wo_t | 8 wi_t | 16 wo2_t | 24 xn | 32 qb|kb|vb [3][4096][1024]
//  | 56 vt | 64 ao | 72 hn | 80 g(32MB) = 112MB
// ---------------------------------------------------------------------------
extern "C" void kernel_launch(void* const* d_in, const int* in_sizes, int n_in,
                              void* d_out, int out_size, void* d_ws, size_t ws_size,
                              hipStream_t stream) {
    const float* x     = (const float*)d_in[0];
    const float* wq    = (const float*)d_in[1];
    const float* wk    = (const float*)d_in[2];
    const float* wv    = (const float*)d_in[3];
    const float* wo    = (const float*)d_in[4];
    const float* w_in  = (const float*)d_in[5];
    const float* w_out = (const float*)d_in[6];
    float* out = (float*)d_out;
    char* ws = (char*)d_ws;
    const size_t MB = 1024 * 1024;
    u16* wq_t  = (u16*)(ws + 0 * MB);   // [3072][1024] fused (wq|wk|wv)
    u16* wo_t  = (u16*)(ws + 6 * MB);
    u16* wi_t  = (u16*)(ws + 8 * MB);
    u16* wo2_t = (u16*)(ws + 16 * MB);
    u16* xn    = (u16*)(ws + 24 * MB);
    u16* qb    = (u16*)(ws + 32 * MB);  // q|k|v contiguous [3][4096][1024]
    u16* vb    = (u16*)(ws + 48 * MB);
    u16* vt    = (u16*)(ws + 56 * MB);
    u16* ao    = (u16*)(ws + 64 * MB);
    u16* hn    = (u16*)(ws + 72 * MB);
    u16* gbuf  = (u16*)(ws + 80 * MB);

    dim3 blk(256);
    // all weights -> bf16 transposed [N][K], single launch
    wtrans_all<<<dim3(3072), blk, 0, stream>>>(wq, wk, wv, wo, w_in, w_out, ws);

    srmsnorm_bf16<<<MM, blk, 0, stream>>>(x, xn);
    // fused QKV: N=3072, epilogue scatters into qb/kb/vb
    gemm_bf16<128, 128, 3><<<dim3(3072 / 128, MM / 128), blk, 0, stream>>>(
        xn, wq_t, nullptr, qb, MM, 3072, DD);
    vtrans<<<dim3(SS / 64, BB * HH), blk, 0, stream>>>(vb, vt);
    attn_mfma<<<dim3(32 * 64), dim3(64), 0, stream>>>(qb, qb + (size_t)MM * 1024, vt, ao);
    gemm_bf16<128, 128, 1><<<dim3(DD / 128, MM / 128), blk, 0, stream>>>(ao, wo_t, x, out, MM, DD, DD); // h
    srmsnorm_bf16<<<MM, blk, 0, stream>>>(out, hn);
    gemm_bf16<128, 128, 2><<<dim3(FF / 128, MM / 128), blk, 0, stream>>>(hn, wi_t, nullptr, gbuf, MM, FF, DD);
    gemm_bf16<128, 128, 1><<<dim3(DD / 128, MM / 128), blk, 0, stream>>>(gbuf, wo2_t, out, out, MM, DD, FF); // h+ff
}

// Round 8
// 418.527 us; speedup vs baseline: 1.1168x; 1.0280x over previous
//
#include <hip/hip_runtime.h>
#include <math.h>

// B=2, S=2048, D=1024, F=4096, H=16, hd=64
#define BB 2
#define SS 2048
#define DD 1024
#define FF 4096
#define HH 16
#define MM (BB * SS)  // 4096

typedef __attribute__((ext_vector_type(8))) short short8v;
typedef __attribute__((ext_vector_type(4))) float float4v;
typedef __attribute__((ext_vector_type(4))) unsigned short ushort4v;
typedef __attribute__((ext_vector_type(8))) unsigned short ushort8v;
typedef unsigned short u16;
typedef unsigned int u32;

#define MFMA16(A_, B_, C_) __builtin_amdgcn_mfma_f32_16x16x32_bf16((A_), (B_), (C_), 0, 0, 0)

__device__ __forceinline__ u16 f2bf(float f) {  // RNE float->bf16
    u32 u = __float_as_uint(f);
    u += 0x7FFF + ((u >> 16) & 1);
    return (u16)(u >> 16);
}

__device__ __forceinline__ void async16(void* lds, const void* g) {
    __builtin_amdgcn_global_load_lds(
        (const __attribute__((address_space(1))) u32*)g,
        (__attribute__((address_space(3))) u32*)lds, 16, 0, 0);
}

__device__ __forceinline__ float gelu_f(float x) {
    // 0.5x(1+tanh(0.79788456(x+0.044715x^3))), tanh via exp2
    float u = 0.7978845608028654f * x * (1.0f + 0.044715f * x * x);
    float e = exp2f(u * 2.8853900817779268f);   // e^{2u}
    float th = 1.0f - 2.0f / (e + 1.0f);
    return 0.5f * x * (1.0f + th);
}

// ---------------------------------------------------------------------------
// srmsnorm: f32 in -> bf16 out. One block per row, 256 thr, float4/thread.
// ---------------------------------------------------------------------------
__global__ __launch_bounds__(256) void srmsnorm_bf16(const float* __restrict__ in,
                                                     u16* __restrict__ out) {
    const int row = blockIdx.x, t = threadIdx.x;
    float4 a = reinterpret_cast<const float4*>(in + (size_t)row * DD)[t];
    float ss = a.x * a.x + a.y * a.y + a.z * a.z + a.w * a.w;
#pragma unroll
    for (int off = 32; off > 0; off >>= 1) ss += __shfl_xor(ss, off);
    __shared__ float red[4];
    if ((t & 63) == 0) red[t >> 6] = ss;
    __syncthreads();
    float tot = red[0] + red[1] + red[2] + red[3];
    float sc = 32.0f / fmaxf(sqrtf(tot), 1e-12f);   // sqrt(1024)=32
    ushort4v ov;
    ov[0] = f2bf(a.x * sc); ov[1] = f2bf(a.y * sc);
    ov[2] = f2bf(a.z * sc); ov[3] = f2bf(a.w * sc);
    *(ushort4v*)(out + (size_t)row * DD + t * 4) = ov;
}

// ---------------------------------------------------------------------------
// ALL weight transposes fused into one launch. in f32 [K][N] -> out bf16
// [N][K], 64x64 tiles.
// ---------------------------------------------------------------------------
__device__ __forceinline__ void trans_tile(const float* __restrict__ in,
                                           u16* __restrict__ out, int K, int N,
                                           int n0, int k0, int t, float (*T)[65]) {
#pragma unroll
    for (int i = 0; i < 4; ++i) {
        int r = i * 16 + (t >> 4), c4 = (t & 15) * 4;
        float4 v = *reinterpret_cast<const float4*>(in + (size_t)(k0 + r) * N + n0 + c4);
        T[r][c4 + 0] = v.x; T[r][c4 + 1] = v.y; T[r][c4 + 2] = v.z; T[r][c4 + 3] = v.w;
    }
    __syncthreads();
#pragma unroll
    for (int i = 0; i < 4; ++i) {
        int r = i * 16 + (t >> 4), c4 = (t & 15) * 4;
        ushort4v ov;
#pragma unroll
        for (int j = 0; j < 4; ++j) ov[j] = f2bf(T[c4 + j][r]);
        *(ushort4v*)(out + (size_t)(n0 + r) * K + k0 + c4) = ov;
    }
}

__global__ __launch_bounds__(256) void wtrans_all(const float* __restrict__ wq,
                                                  const float* __restrict__ wk,
                                                  const float* __restrict__ wv,
                                                  const float* __restrict__ wo,
                                                  const float* __restrict__ wi,
                                                  const float* __restrict__ wo2,
                                                  char* __restrict__ ws) {
    __shared__ float T[64][65];
    const int t = threadIdx.x;
    const size_t MB = 1024 * 1024;
    int id = blockIdx.x;
    if (id < 1024) {
        const int which = id >> 8, l = id & 255;
        const float* in = which == 0 ? wq : which == 1 ? wk : which == 2 ? wv : wo;
        u16* out = (u16*)(ws + (size_t)which * 2 * MB);   // 0,2,4,6 MB
        trans_tile(in, out, 1024, 1024, (l & 15) * 64, (l >> 4) * 64, t, T);
    } else if (id < 2048) {
        const int l = id - 1024;
        trans_tile(wi, (u16*)(ws + 8 * MB), 1024, 4096,
                   (l & 63) * 64, (l >> 6) * 64, t, T);
    } else {
        const int l = id - 2048;
        trans_tile(wo2, (u16*)(ws + 16 * MB), 4096, 1024,
                   (l & 15) * 64, (l >> 4) * 64, t, T);
    }
}

// ---------------------------------------------------------------------------
// V transpose: vb bf16 [B*S][D] -> vt bf16 [B*H][64][S]. pad 88 keeps 16B
// stores aligned.
// ---------------------------------------------------------------------------
__global__ __launch_bounds__(256) void vtrans(const u16* __restrict__ vb,
                                              u16* __restrict__ vt) {
    __shared__ u16 T[64][88];
    const int t = threadIdx.x;
    const int s0 = blockIdx.x * 64, bh = blockIdx.y;
    const int b = bh >> 4, h = bh & 15;
#pragma unroll
    for (int i = 0; i < 2; ++i) {
        int r = i * 32 + (t >> 3), c8 = (t & 7) * 8;
        *(ushort8v*)&T[r][c8] =
            *(const ushort8v*)(vb + (size_t)(b * SS + s0 + r) * DD + h * 64 + c8);
    }
    __syncthreads();
#pragma unroll
    for (int i = 0; i < 2; ++i) {
        int d = i * 32 + (t >> 3), s8 = (t & 7) * 8;
        ushort8v ov;
#pragma unroll
        for (int j = 0; j < 8; ++j) ov[j] = T[s8 + j][d];
        *(ushort8v*)(vt + ((size_t)bh * 64 + d) * SS + s0 + s8) = ov;
    }
}

// ---------------------------------------------------------------------------
// bf16 MFMA GEMM (m97 structure): C[M,N] = A[M,K] * Bt[N,K]^T
// BK=32, 256 thr = 4 waves (2x2), global_load_lds width 16, 2 barriers/K-step.
// Bijective XCD swizzle (m204) on the linearized block id for L2 locality.
// EPI 0: bf16 out. EPI 1: f32 out = acc + Res. EPI 2: bf16 out = gelu(acc).
// EPI 3: fused-QKV scatter into 3 contiguous [M][1024] bf16 bufs.
// ---------------------------------------------------------------------------
template <int BM, int BN, int EPI>
__global__ __launch_bounds__(256) void gemm_bf16(const u16* __restrict__ A,
                                                 const u16* __restrict__ Bt,
                                                 const float* __restrict__ Res,
                                                 void* __restrict__ Cout,
                                                 int M, int N, int K) {
    __shared__ u16 As[BM * 32];
    __shared__ u16 Bs[BN * 32];
    constexpr int FM = BM / 32, FN = BN / 32;
    const int t = threadIdx.x;
    const int w = t >> 6, lane = t & 63;
    const int g = lane >> 4, c = lane & 15;
    const int wr = w >> 1, wc = w & 1;
    // XCD-aware bijective swizzle of the linear block id (m204)
    const int gx = gridDim.x;
    const int nwg = gx * gridDim.y;
    int wg = blockIdx.y * gx + blockIdx.x;
    {
        const int q = nwg >> 3, rr = nwg & 7;
        const int xcd = wg & 7, loc = wg >> 3;
        wg = (xcd < rr) ? xcd * (q + 1) + loc
                        : rr * (q + 1) + (xcd - rr) * q + loc;
    }
    const int bm = (wg / gx) * BM, bn = (wg % gx) * BN;
    const int arow = t >> 2, au = (t & 3) * 8;   // staging: 16B per thread

    float4v acc[FM][FN] = {};
    for (int k0 = 0; k0 < K; k0 += 32) {
        __syncthreads();   // prev iteration's LDS reads done
#pragma unroll
        for (int p = 0; p < BM / 64; ++p)
            async16(&As[(p * 64 + arow) * 32 + au],
                    A + (size_t)(bm + p * 64 + arow) * K + k0 + au);
#pragma unroll
        for (int p = 0; p < BN / 64; ++p)
            async16(&Bs[(p * 64 + arow) * 32 + au],
                    Bt + (size_t)(bn + p * 64 + arow) * K + k0 + au);
        __syncthreads();   // drains vmcnt -> LDS visible
        short8v af[FM], bf[FN];
#pragma unroll
        for (int mi = 0; mi < FM; ++mi)
            af[mi] = *(const short8v*)&As[(wr * (BM / 2) + mi * 16 + c) * 32 + g * 8];
#pragma unroll
        for (int ni = 0; ni < FN; ++ni)
            bf[ni] = *(const short8v*)&Bs[(wc * (BN / 2) + ni * 16 + c) * 32 + g * 8];
#pragma unroll
        for (int mi = 0; mi < FM; ++mi)
#pragma unroll
            for (int ni = 0; ni < FN; ++ni)
                acc[mi][ni] = MFMA16(af[mi], bf[ni], acc[mi][ni]);
    }
    const int row0 = bm + wr * (BM / 2), col0 = bn + wc * (BN / 2);
    if (EPI == 3) {
        const int seg = col0 >> 10, c0 = col0 & 1023;
        u16* dst = (u16*)Cout + (size_t)seg * ((size_t)MM * 1024);
#pragma unroll
        for (int mi = 0; mi < FM; ++mi)
#pragma unroll
            for (int r = 0; r < 4; ++r) {
                const size_t rw = (size_t)(row0 + mi * 16 + 4 * g + r) * 1024;
#pragma unroll
                for (int ni = 0; ni < FN; ++ni)
                    dst[rw + c0 + ni * 16 + c] = f2bf(acc[mi][ni][r]);
            }
        return;
    }
#pragma unroll
    for (int mi = 0; mi < FM; ++mi)
#pragma unroll
        for (int r = 0; r < 4; ++r) {
            const size_t rw = (size_t)(row0 + mi * 16 + 4 * g + r) * N;
#pragma unroll
            for (int ni = 0; ni < FN; ++ni) {
                const size_t off = rw + col0 + ni * 16 + c;
                float v = acc[mi][ni][r];
                if (EPI == 0)      ((u16*)Cout)[off] = f2bf(v);
                else if (EPI == 1) ((float*)Cout)[off] = v + Res[off];
                else               ((u16*)Cout)[off] = f2bf(gelu_f(v));
            }
        }
}

// ---------------------------------------------------------------------------
// Causal flash attention, split-K (flash-decoding). One 64-thread block =
// one wave = one 32-q-row unit x one kv-half. 4096 blocks (2x round-6 wave
// count, same total per-kt work) -> occupancy 12.5% -> ~25-30%.
// Partials: unnormalized O (f32) + per-row (m, l) -> combined by attn_comb.
// ---------------------------------------------------------------------------
__global__ __launch_bounds__(64) void attn_split(const u16* __restrict__ Qb,
                                                 const u16* __restrict__ Kb,
                                                 const u16* __restrict__ Vt,
                                                 float* __restrict__ po,
                                                 float* __restrict__ pml) {
    __shared__ u16 Pl[2][16][88];
    const int lane = threadIdx.x;
    const int g = lane >> 4, c = lane & 15;
    const int bid = blockIdx.x;
    const int s = bid & 1;
    const int uid = bid >> 1;                // 2048 units
    const int bh = uid & 31;
    const int u = 63 - (uid >> 5);           // heavy units first
    const int b = bh >> 4, h = bh & 15;
    const int qrow0 = u * 32;
    const int nkt = (u >> 1) + 1;            // kt tiles for this unit
    const int half = (nkt + 1) >> 1;
    const int kt0 = s ? half : 0;
    const int kt1 = s ? nkt : half;
    float* myo = po + ((size_t)(uid * 2 + s)) * 32 * 64;
    float* mym = pml + ((size_t)(uid * 2 + s)) * 2 * 32;

    if (kt0 >= kt1) {   // empty split (nkt==1, s==1): neutral partial
#pragma unroll
        for (int rb = 0; rb < 2; ++rb)
#pragma unroll
            for (int nb = 0; nb < 4; ++nb)
#pragma unroll
                for (int r = 0; r < 4; ++r)
                    myo[(rb * 16 + 4 * g + r) * 64 + nb * 16 + c] = 0.0f;
        if (c == 0)
#pragma unroll
            for (int rb = 0; rb < 2; ++rb)
#pragma unroll
                for (int r = 0; r < 4; ++r) {
                    mym[rb * 16 + 4 * g + r] = -1e30f;       // m
                    mym[32 + rb * 16 + 4 * g + r] = 0.0f;    // l
                }
        return;
    }

    const size_t qkbase = (size_t)b * SS * DD + h * 64;
    const size_t vbase = (size_t)bh * 64 * SS;
    constexpr float SC = 0.18033688011112042f;  // 0.125 * log2(e)

    short8v qf[2][2];
#pragma unroll
    for (int rb = 0; rb < 2; ++rb)
#pragma unroll
        for (int kh = 0; kh < 2; ++kh)
            qf[rb][kh] = *(const short8v*)(Qb + qkbase +
                             (size_t)(qrow0 + rb * 16 + c) * DD + kh * 32 + g * 8);

    float4v o[2][4] = {};
    float m_run[2][4], l_run[2][4];
#pragma unroll
    for (int rb = 0; rb < 2; ++rb)
#pragma unroll
        for (int r = 0; r < 4; ++r) { m_run[rb][r] = -1e30f; l_run[rb][r] = 0.0f; }

    for (int kt = kt0; kt < kt1; ++kt) {
        // ---- scores S = Q K^T ----
        short8v kf[4][2];
#pragma unroll
        for (int nb = 0; nb < 4; ++nb)
#pragma unroll
            for (int kh = 0; kh < 2; ++kh)
                kf[nb][kh] = *(const short8v*)(Kb + qkbase +
                                 (size_t)(kt * 64 + nb * 16 + c) * DD + kh * 32 + g * 8);
        float4v sa[2][4] = {};
        __builtin_amdgcn_s_setprio(1);
#pragma unroll
        for (int nb = 0; nb < 4; ++nb)
#pragma unroll
            for (int kh = 0; kh < 2; ++kh)
#pragma unroll
                for (int rb = 0; rb < 2; ++rb)
                    sa[rb][nb] = MFMA16(qf[rb][kh], kf[nb][kh], sa[rb][nb]);
        __builtin_amdgcn_s_setprio(0);

        const bool diag = (kt == nkt - 1);   // only last tile has masked entries
#pragma unroll
        for (int rb = 0; rb < 2; ++rb)
#pragma unroll
            for (int nb = 0; nb < 4; ++nb)
#pragma unroll
                for (int r = 0; r < 4; ++r) {
                    float v = sa[rb][nb][r] * SC;
                    if (diag && (kt * 64 + nb * 16 + c > qrow0 + rb * 16 + 4 * g + r))
                        v = -3e38f;
                    sa[rb][nb][r] = v;
                }

        // ---- online softmax (rows live in 16-lane groups) ----
#pragma unroll
        for (int rb = 0; rb < 2; ++rb) {
            float corr[4];
#pragma unroll
            for (int r = 0; r < 4; ++r) {
                float m0 = fmaxf(fmaxf(sa[rb][0][r], sa[rb][1][r]),
                                 fmaxf(sa[rb][2][r], sa[rb][3][r]));
                m0 = fmaxf(m0, __shfl_xor(m0, 1));
                m0 = fmaxf(m0, __shfl_xor(m0, 2));
                m0 = fmaxf(m0, __shfl_xor(m0, 4));
                m0 = fmaxf(m0, __shfl_xor(m0, 8));
                float mn = fmaxf(m_run[rb][r], m0);
                corr[r] = exp2f(m_run[rb][r] - mn);
                m_run[rb][r] = mn;
            }
#pragma unroll
            for (int nb = 0; nb < 4; ++nb)
#pragma unroll
                for (int r = 0; r < 4; ++r)
                    sa[rb][nb][r] = exp2f(sa[rb][nb][r] - m_run[rb][r]);
#pragma unroll
            for (int r = 0; r < 4; ++r) {
                float s_ = sa[rb][0][r] + sa[rb][1][r] + sa[rb][2][r] + sa[rb][3][r];
                s_ += __shfl_xor(s_, 1); s_ += __shfl_xor(s_, 2);
                s_ += __shfl_xor(s_, 4); s_ += __shfl_xor(s_, 8);
                l_run[rb][r] = l_run[rb][r] * corr[r] + s_;
            }
            float4v cv; cv[0] = corr[0]; cv[1] = corr[1]; cv[2] = corr[2]; cv[3] = corr[3];
#pragma unroll
            for (int nb = 0; nb < 4; ++nb) o[rb][nb] *= cv;
            // P -> bf16 -> LDS (lane transpose); same-wave DS ordering, no barrier
#pragma unroll
            for (int nb = 0; nb < 4; ++nb)
#pragma unroll
                for (int r = 0; r < 4; ++r)
                    Pl[rb][4 * g + r][nb * 16 + c] = f2bf(sa[rb][nb][r]);
        }

        // ---- O += P V ----
        short8v pa[2][2];
#pragma unroll
        for (int rb = 0; rb < 2; ++rb)
#pragma unroll
            for (int kh = 0; kh < 2; ++kh)
                pa[rb][kh] = *(const short8v*)&Pl[rb][c][kh * 32 + g * 8];
        short8v vf[4][2];
#pragma unroll
        for (int nb = 0; nb < 4; ++nb)
#pragma unroll
            for (int kh = 0; kh < 2; ++kh)
                vf[nb][kh] = *(const short8v*)(Vt + vbase +
                                 (size_t)(nb * 16 + c) * SS + kt * 64 + kh * 32 + g * 8);
        __builtin_amdgcn_s_setprio(1);
#pragma unroll
        for (int nb = 0; nb < 4; ++nb)
#pragma unroll
            for (int kh = 0; kh < 2; ++kh)
#pragma unroll
                for (int rb = 0; rb < 2; ++rb)
                    o[rb][nb] = MFMA16(pa[rb][kh], vf[nb][kh], o[rb][nb]);
        __builtin_amdgcn_s_setprio(0);
    }

    // epilogue: store unnormalized O + (m, l)
#pragma unroll
    for (int rb = 0; rb < 2; ++rb)
#pragma unroll
        for (int nb = 0; nb < 4; ++nb)
#pragma unroll
            for (int r = 0; r < 4; ++r)
                myo[(rb * 16 + 4 * g + r) * 64 + nb * 16 + c] = o[rb][nb][r];
    if (c == 0)
#pragma unroll
        for (int rb = 0; rb < 2; ++rb)
#pragma unroll
            for (int r = 0; r < 4; ++r) {
                mym[rb * 16 + 4 * g + r] = m_run[rb][r];
                mym[32 + rb * 16 + 4 * g + r] = l_run[rb][r];
            }
}

// ---------------------------------------------------------------------------
// Combine split partials: out = (e0*o0 + e1*o1) / (e0*l0 + e1*l1), bf16.
// 2048 blocks x 256 thr; thread -> (row = t>>3, 8 cols at (t&7)*8).
// ---------------------------------------------------------------------------
__global__ __launch_bounds__(256) void attn_comb(const float* __restrict__ po,
                                                 const float* __restrict__ pml,
                                                 u16* __restrict__ Ao) {
    const int uid = blockIdx.x;
    const int bh = uid & 31;
    const int u = 63 - (uid >> 5);
    const int b = bh >> 4, h = bh & 15;
    const int qrow0 = u * 32;
    const int t = threadIdx.x;
    const int row = t >> 3, c8 = (t & 7) * 8;

    const float* ml0 = pml + (size_t)(uid * 2 + 0) * 64;
    const float* ml1 = pml + (size_t)(uid * 2 + 1) * 64;
    const float m0 = ml0[row], l0 = ml0[32 + row];
    const float m1 = ml1[row], l1 = ml1[32 + row];
    const float mm = fmaxf(m0, m1);
    const float e0 = exp2f(m0 - mm), e1 = exp2f(m1 - mm);
    const float inv = 1.0f / (e0 * l0 + e1 * l1);

    const float* o0 = po + ((size_t)(uid * 2 + 0) * 32 + row) * 64 + c8;
    const float* o1 = po + ((size_t)(uid * 2 + 1) * 32 + row) * 64 + c8;
    float4 a0 = *(const float4*)o0, b0 = *(const float4*)(o0 + 4);
    float4 a1 = *(const float4*)o1, b1 = *(const float4*)(o1 + 4);
    ushort8v ov;
    ov[0] = f2bf((e0 * a0.x + e1 * a1.x) * inv);
    ov[1] = f2bf((e0 * a0.y + e1 * a1.y) * inv);
    ov[2] = f2bf((e0 * a0.z + e1 * a1.z) * inv);
    ov[3] = f2bf((e0 * a0.w + e1 * a1.w) * inv);
    ov[4] = f2bf((e0 * b0.x + e1 * b1.x) * inv);
    ov[5] = f2bf((e0 * b0.y + e1 * b1.y) * inv);
    ov[6] = f2bf((e0 * b0.z + e1 * b1.z) * inv);
    ov[7] = f2bf((e0 * b0.w + e1 * b1.w) * inv);
    *(ushort8v*)(Ao + (size_t)b * SS * DD + (size_t)(qrow0 + row) * DD + h * 64 + c8) = ov;
}

// ---------------------------------------------------------------------------
// launch: h = x + attn(srmsnorm(x)); out = h + gelu(srmsnorm(h)@w_in)@w_out
// ws layout (MB): 0 wq_t|2 wk_t|4 wv_t (fused [3072][1024]) | 6 wo_t | 8 wi_t
//  | 16 wo2_t | 24 xn (reused: pml after QKV gemm) | 32 qb|kb|vb [3][4096][1024]
//  | 56 vt | 64 ao | 72 hn | 80 gbuf(32MB, also attn po partials —
//  temporally disjoint). Total 112 MB (same proven-safe footprint).
// ---------------------------------------------------------------------------
extern "C" void kernel_launch(void* const* d_in, const int* in_sizes, int n_in,
                              void* d_out, int out_size, void* d_ws, size_t ws_size,
                              hipStream_t stream) {
    const float* x     = (const float*)d_in[0];
    const float* wq    = (const float*)d_in[1];
    const float* wk    = (const float*)d_in[2];
    const float* wv    = (const float*)d_in[3];
    const float* wo    = (const float*)d_in[4];
    const float* w_in  = (const float*)d_in[5];
    const float* w_out = (const float*)d_in[6];
    float* out = (float*)d_out;
    char* ws = (char*)d_ws;
    const size_t MB = 1024 * 1024;
    u16* wq_t  = (u16*)(ws + 0 * MB);   // [3072][1024] fused (wq|wk|wv)
    u16* wo_t  = (u16*)(ws + 6 * MB);
    u16* wi_t  = (u16*)(ws + 8 * MB);
    u16* wo2_t = (u16*)(ws + 16 * MB);
    u16* xn    = (u16*)(ws + 24 * MB);
    u16* qb    = (u16*)(ws + 32 * MB);  // q|k|v contiguous [3][4096][1024]
    u16* vb    = (u16*)(ws + 48 * MB);
    u16* vt    = (u16*)(ws + 56 * MB);
    u16* ao    = (u16*)(ws + 64 * MB);
    u16* hn    = (u16*)(ws + 72 * MB);
    u16* gbuf  = (u16*)(ws + 80 * MB);
    float* po  = (float*)(ws + 80 * MB);   // 32MB partial O (dead before gbuf)
    float* pml = (float*)(ws + 24 * MB);   // 1MB partial (m,l); xn dead by then

    dim3 blk(256);
    // all weights -> bf16 transposed [N][K], single launch
    wtrans_all<<<dim3(3072), blk, 0, stream>>>(wq, wk, wv, wo, w_in, w_out, ws);

    srmsnorm_bf16<<<MM, blk, 0, stream>>>(x, xn);
    // fused QKV: N=3072, epilogue scatters into qb/kb/vb
    gemm_bf16<128, 128, 3><<<dim3(3072 / 128, MM / 128), blk, 0, stream>>>(
        xn, wq_t, nullptr, qb, MM, 3072, DD);
    vtrans<<<dim3(SS / 64, BB * HH), blk, 0, stream>>>(vb, vt);
    attn_split<<<dim3(32 * 64 * 2), dim3(64), 0, stream>>>(
        qb, qb + (size_t)MM * 1024, vt, po, pml);
    attn_comb<<<dim3(2048), blk, 0, stream>>>(po, pml, ao);
    gemm_bf16<128, 128, 1><<<dim3(DD / 128, MM / 128), blk, 0, stream>>>(ao, wo_t, x, out, MM, DD, DD); // h
    srmsnorm_bf16<<<MM, blk, 0, stream>>>(out, hn);
    gemm_bf16<128, 128, 2><<<dim3(FF / 128, MM / 128), blk, 0, stream>>>(hn, wi_t, nullptr, gbuf, MM, FF, DD);
    gemm_bf16<128, 128, 1><<<dim3(DD / 128, MM / 128), blk, 0, stream>>>(gbuf, wo2_t, out, out, MM, DD, FF); // h+ff
}

// Round 11
// 416.849 us; speedup vs baseline: 1.1213x; 1.0040x over previous
//
#include <hip/hip_runtime.h>
#include <math.h>

// B=2, S=2048, D=1024, F=4096, H=16, hd=64
#define BB 2
#define SS 2048
#define DD 1024
#define FF 4096
#define HH 16
#define MM (BB * SS)  // 4096

typedef __attribute__((ext_vector_type(8))) short short8v;
typedef __attribute__((ext_vector_type(4))) float float4v;
typedef __attribute__((ext_vector_type(4))) unsigned short ushort4v;
typedef __attribute__((ext_vector_type(8))) unsigned short ushort8v;
typedef unsigned short u16;
typedef unsigned int u32;

#define MFMA16(A_, B_, C_) __builtin_amdgcn_mfma_f32_16x16x32_bf16((A_), (B_), (C_), 0, 0, 0)

__device__ __forceinline__ u16 f2bf(float f) {  // RNE float->bf16
    u32 u = __float_as_uint(f);
    u += 0x7FFF + ((u >> 16) & 1);
    return (u16)(u >> 16);
}

__device__ __forceinline__ void async16(void* lds, const void* g) {
    __builtin_amdgcn_global_load_lds(
        (const __attribute__((address_space(1))) u32*)g,
        (__attribute__((address_space(3))) u32*)lds, 16, 0, 0);
}

__device__ __forceinline__ float gelu_f(float x) {
    // 0.5x(1+tanh(0.79788456(x+0.044715x^3))), tanh via exp2
    float u = 0.7978845608028654f * x * (1.0f + 0.044715f * x * x);
    float e = exp2f(u * 2.8853900817779268f);   // e^{2u}
    float th = 1.0f - 2.0f / (e + 1.0f);
    return 0.5f * x * (1.0f + th);
}

// ---------------------------------------------------------------------------
// srmsnorm: f32 in -> bf16 out. One block per row, 256 thr, float4/thread.
// ---------------------------------------------------------------------------
__global__ __launch_bounds__(256) void srmsnorm_bf16(const float* __restrict__ in,
                                                     u16* __restrict__ out) {
    const int row = blockIdx.x, t = threadIdx.x;
    float4 a = reinterpret_cast<const float4*>(in + (size_t)row * DD)[t];
    float ss = a.x * a.x + a.y * a.y + a.z * a.z + a.w * a.w;
#pragma unroll
    for (int off = 32; off > 0; off >>= 1) ss += __shfl_xor(ss, off);
    __shared__ float red[4];
    if ((t & 63) == 0) red[t >> 6] = ss;
    __syncthreads();
    float tot = red[0] + red[1] + red[2] + red[3];
    float sc = 32.0f / fmaxf(sqrtf(tot), 1e-12f);   // sqrt(1024)=32
    ushort4v ov;
    ov[0] = f2bf(a.x * sc); ov[1] = f2bf(a.y * sc);
    ov[2] = f2bf(a.z * sc); ov[3] = f2bf(a.w * sc);
    *(ushort4v*)(out + (size_t)row * DD + t * 4) = ov;
}

// ---------------------------------------------------------------------------
// ALL weight transposes fused into one launch. in f32 [K][N] -> out bf16
// [N][K], 64x64 tiles.
// ---------------------------------------------------------------------------
__device__ __forceinline__ void trans_tile(const float* __restrict__ in,
                                           u16* __restrict__ out, int K, int N,
                                           int n0, int k0, int t, float (*T)[65]) {
#pragma unroll
    for (int i = 0; i < 4; ++i) {
        int r = i * 16 + (t >> 4), c4 = (t & 15) * 4;
        float4 v = *reinterpret_cast<const float4*>(in + (size_t)(k0 + r) * N + n0 + c4);
        T[r][c4 + 0] = v.x; T[r][c4 + 1] = v.y; T[r][c4 + 2] = v.z; T[r][c4 + 3] = v.w;
    }
    __syncthreads();
#pragma unroll
    for (int i = 0; i < 4; ++i) {
        int r = i * 16 + (t >> 4), c4 = (t & 15) * 4;
        ushort4v ov;
#pragma unroll
        for (int j = 0; j < 4; ++j) ov[j] = f2bf(T[c4 + j][r]);
        *(ushort4v*)(out + (size_t)(n0 + r) * K + k0 + c4) = ov;
    }
}

__global__ __launch_bounds__(256) void wtrans_all(const float* __restrict__ wq,
                                                  const float* __restrict__ wk,
                                                  const float* __restrict__ wv,
                                                  const float* __restrict__ wo,
                                                  const float* __restrict__ wi,
                                                  const float* __restrict__ wo2,
                                                  char* __restrict__ ws) {
    __shared__ float T[64][65];
    const int t = threadIdx.x;
    const size_t MB = 1024 * 1024;
    int id = blockIdx.x;
    if (id < 1024) {
        const int which = id >> 8, l = id & 255;
        const float* in = which == 0 ? wq : which == 1 ? wk : which == 2 ? wv : wo;
        u16* out = (u16*)(ws + (size_t)which * 2 * MB);   // 0,2,4,6 MB
        trans_tile(in, out, 1024, 1024, (l & 15) * 64, (l >> 4) * 64, t, T);
    } else if (id < 2048) {
        const int l = id - 1024;
        trans_tile(wi, (u16*)(ws + 8 * MB), 1024, 4096,
                   (l & 63) * 64, (l >> 6) * 64, t, T);
    } else {
        const int l = id - 2048;
        trans_tile(wo2, (u16*)(ws + 16 * MB), 4096, 1024,
                   (l & 15) * 64, (l >> 4) * 64, t, T);
    }
}

// ---------------------------------------------------------------------------
// V transpose: vb bf16 [B*S][D] -> vt bf16 [B*H][64][S]. pad 88 keeps 16B
// stores aligned.
// ---------------------------------------------------------------------------
__global__ __launch_bounds__(256) void vtrans(const u16* __restrict__ vb,
                                              u16* __restrict__ vt) {
    __shared__ u16 T[64][88];
    const int t = threadIdx.x;
    const int s0 = blockIdx.x * 64, bh = blockIdx.y;
    const int b = bh >> 4, h = bh & 15;
#pragma unroll
    for (int i = 0; i < 2; ++i) {
        int r = i * 32 + (t >> 3), c8 = (t & 7) * 8;
        *(ushort8v*)&T[r][c8] =
            *(const ushort8v*)(vb + (size_t)(b * SS + s0 + r) * DD + h * 64 + c8);
    }
    __syncthreads();
#pragma unroll
    for (int i = 0; i < 2; ++i) {
        int d = i * 32 + (t >> 3), s8 = (t & 7) * 8;
        ushort8v ov;
#pragma unroll
        for (int j = 0; j < 8; ++j) ov[j] = T[s8 + j][d];
        *(ushort8v*)(vt + ((size_t)bh * 64 + d) * SS + s0 + s8) = ov;
    }
}

// ---------------------------------------------------------------------------
// bf16 MFMA GEMM (m97 structure): C[M,N] = A[M,K] * Bt[N,K]^T
// BK=32, 256 thr = 4 waves (2x2), global_load_lds width 16, 2 barriers/K-step.
// Bijective XCD swizzle (m204) per z-plane.
// EPI 0: bf16 out. EPI 1: f32 out = acc + Res. EPI 2: bf16 out = gelu(acc).
// EPI 3: fused-QKV scatter into 3 contiguous [M][1024] bf16 bufs.
// EPI 4: split-K partial — z-plane p computes K/gridDim.z slice, stores raw
//        f32 acc to ((float*)Cout) + z*M*N. Combined by add2_f32.
// ---------------------------------------------------------------------------
template <int BM, int BN, int EPI>
__global__ __launch_bounds__(256) void gemm_bf16(const u16* __restrict__ A,
                                                 const u16* __restrict__ Bt,
                                                 const float* __restrict__ Res,
                                                 void* __restrict__ Cout,
                                                 int M, int N, int K) {
    __shared__ u16 As[BM * 32];
    __shared__ u16 Bs[BN * 32];
    constexpr int FM = BM / 32, FN = BN / 32;
    const int t = threadIdx.x;
    const int w = t >> 6, lane = t & 63;
    const int g = lane >> 4, c = lane & 15;
    const int wr = w >> 1, wc = w & 1;
    // XCD-aware bijective swizzle of the linear block id (m204), per z-plane
    const int gx = gridDim.x;
    const int nwg = gx * gridDim.y;
    int wg = blockIdx.y * gx + blockIdx.x;
    {
        const int q = nwg >> 3, rr = nwg & 7;
        const int xcd = wg & 7, loc = wg >> 3;
        wg = (xcd < rr) ? xcd * (q + 1) + loc
                        : rr * (q + 1) + (xcd - rr) * q + loc;
    }
    const int bm = (wg / gx) * BM, bn = (wg % gx) * BN;
    const int arow = t >> 2, au = (t & 3) * 8;   // staging: 16B per thread
    // split-K range (gridDim.z == 1 for non-split launches)
    const int kseg = K / (int)gridDim.z;
    const int kbeg = (int)blockIdx.z * kseg, kend = kbeg + kseg;

    float4v acc[FM][FN] = {};
    for (int k0 = kbeg; k0 < kend; k0 += 32) {
        __syncthreads();   // prev iteration's LDS reads done
#pragma unroll
        for (int p = 0; p < BM / 64; ++p)
            async16(&As[(p * 64 + arow) * 32 + au],
                    A + (size_t)(bm + p * 64 + arow) * K + k0 + au);
#pragma unroll
        for (int p = 0; p < BN / 64; ++p)
            async16(&Bs[(p * 64 + arow) * 32 + au],
                    Bt + (size_t)(bn + p * 64 + arow) * K + k0 + au);
        __syncthreads();   // drains vmcnt -> LDS visible
        short8v af[FM], bf[FN];
#pragma unroll
        for (int mi = 0; mi < FM; ++mi)
            af[mi] = *(const short8v*)&As[(wr * (BM / 2) + mi * 16 + c) * 32 + g * 8];
#pragma unroll
        for (int ni = 0; ni < FN; ++ni)
            bf[ni] = *(const short8v*)&Bs[(wc * (BN / 2) + ni * 16 + c) * 32 + g * 8];
#pragma unroll
        for (int mi = 0; mi < FM; ++mi)
#pragma unroll
            for (int ni = 0; ni < FN; ++ni)
                acc[mi][ni] = MFMA16(af[mi], bf[ni], acc[mi][ni]);
    }
    const int row0 = bm + wr * (BM / 2), col0 = bn + wc * (BN / 2);
    if (EPI == 3) {
        const int seg = col0 >> 10, c0 = col0 & 1023;
        u16* dst = (u16*)Cout + (size_t)seg * ((size_t)MM * 1024);
#pragma unroll
        for (int mi = 0; mi < FM; ++mi)
#pragma unroll
            for (int r = 0; r < 4; ++r) {
                const size_t rw = (size_t)(row0 + mi * 16 + 4 * g + r) * 1024;
#pragma unroll
                for (int ni = 0; ni < FN; ++ni)
                    dst[rw + c0 + ni * 16 + c] = f2bf(acc[mi][ni][r]);
            }
        return;
    }
    if (EPI == 4) {
        float* dst = (float*)Cout + (size_t)blockIdx.z * M * N;
#pragma unroll
        for (int mi = 0; mi < FM; ++mi)
#pragma unroll
            for (int r = 0; r < 4; ++r) {
                const size_t rw = (size_t)(row0 + mi * 16 + 4 * g + r) * N;
#pragma unroll
                for (int ni = 0; ni < FN; ++ni)
                    dst[rw + col0 + ni * 16 + c] = acc[mi][ni][r];
            }
        return;
    }
#pragma unroll
    for (int mi = 0; mi < FM; ++mi)
#pragma unroll
        for (int r = 0; r < 4; ++r) {
            const size_t rw = (size_t)(row0 + mi * 16 + 4 * g + r) * N;
#pragma unroll
            for (int ni = 0; ni < FN; ++ni) {
                const size_t off = rw + col0 + ni * 16 + c;
                float v = acc[mi][ni][r];
                if (EPI == 0)      ((u16*)Cout)[off] = f2bf(v);
                else if (EPI == 1) ((float*)Cout)[off] = v + Res[off];
                else               ((u16*)Cout)[off] = f2bf(gelu_f(v));
            }
        }
}

// ---------------------------------------------------------------------------
// Split-K combine: out += p0 + p1 (out already holds the residual h).
// 4096 blocks x 256 thr x float4.
// ---------------------------------------------------------------------------
__global__ __launch_bounds__(256) void add2_f32(const float* __restrict__ p0,
                                                const float* __restrict__ p1,
                                                float* __restrict__ out) {
    const size_t i = ((size_t)blockIdx.x * 256 + threadIdx.x) * 4;
    float4 a = *(const float4*)(out + i);
    float4 b = *(const float4*)(p0 + i);
    float4 c = *(const float4*)(p1 + i);
    a.x += b.x + c.x; a.y += b.y + c.y; a.z += b.z + c.z; a.w += b.w + c.w;
    *(float4*)(out + i) = a;
}

// ---------------------------------------------------------------------------
// Causal flash attention, split-K (flash-decoding). One 64-thread block =
// one wave = one 32-q-row unit x one kv-half. 4096 blocks.
// Partials: unnormalized O (f32) + per-row (m, l) -> combined by attn_comb.
// ---------------------------------------------------------------------------
__global__ __launch_bounds__(64) void attn_split(const u16* __restrict__ Qb,
                                                 const u16* __restrict__ Kb,
                                                 const u16* __restrict__ Vt,
                                                 float* __restrict__ po,
                                                 float* __restrict__ pml) {
    __shared__ u16 Pl[2][16][88];
    const int lane = threadIdx.x;
    const int g = lane >> 4, c = lane & 15;
    const int bid = blockIdx.x;
    const int s = bid & 1;
    const int uid = bid >> 1;                // 2048 units
    const int bh = uid & 31;
    const int u = 63 - (uid >> 5);           // heavy units first
    const int b = bh >> 4, h = bh & 15;
    const int qrow0 = u * 32;
    const int nkt = (u >> 1) + 1;            // kt tiles for this unit
    const int half = (nkt + 1) >> 1;
    const int kt0 = s ? half : 0;
    const int kt1 = s ? nkt : half;
    float* myo = po + ((size_t)(uid * 2 + s)) * 32 * 64;
    float* mym = pml + ((size_t)(uid * 2 + s)) * 2 * 32;

    if (kt0 >= kt1) {   // empty split (nkt==1, s==1): neutral partial
#pragma unroll
        for (int rb = 0; rb < 2; ++rb)
#pragma unroll
            for (int nb = 0; nb < 4; ++nb)
#pragma unroll
                for (int r = 0; r < 4; ++r)
                    myo[(rb * 16 + 4 * g + r) * 64 + nb * 16 + c] = 0.0f;
        if (c == 0)
#pragma unroll
            for (int rb = 0; rb < 2; ++rb)
#pragma unroll
                for (int r = 0; r < 4; ++r) {
                    mym[rb * 16 + 4 * g + r] = -1e30f;       // m
                    mym[32 + rb * 16 + 4 * g + r] = 0.0f;    // l
                }
        return;
    }

    const size_t qkbase = (size_t)b * SS * DD + h * 64;
    const size_t vbase = (size_t)bh * 64 * SS;
    constexpr float SC = 0.18033688011112042f;  // 0.125 * log2(e)

    short8v qf[2][2];
#pragma unroll
    for (int rb = 0; rb < 2; ++rb)
#pragma unroll
        for (int kh = 0; kh < 2; ++kh)
            qf[rb][kh] = *(const short8v*)(Qb + qkbase +
                             (size_t)(qrow0 + rb * 16 + c) * DD + kh * 32 + g * 8);

    float4v o[2][4] = {};
    float m_run[2][4], l_run[2][4];
#pragma unroll
    for (int rb = 0; rb < 2; ++rb)
#pragma unroll
        for (int r = 0; r < 4; ++r) { m_run[rb][r] = -1e30f; l_run[rb][r] = 0.0f; }

    for (int kt = kt0; kt < kt1; ++kt) {
        // ---- scores S = Q K^T ----
        short8v kf[4][2];
#pragma unroll
        for (int nb = 0; nb < 4; ++nb)
#pragma unroll
            for (int kh = 0; kh < 2; ++kh)
                kf[nb][kh] = *(const short8v*)(Kb + qkbase +
                                 (size_t)(kt * 64 + nb * 16 + c) * DD + kh * 32 + g * 8);
        float4v sa[2][4] = {};
        __builtin_amdgcn_s_setprio(1);
#pragma unroll
        for (int nb = 0; nb < 4; ++nb)
#pragma unroll
            for (int kh = 0; kh < 2; ++kh)
#pragma unroll
                for (int rb = 0; rb < 2; ++rb)
                    sa[rb][nb] = MFMA16(qf[rb][kh], kf[nb][kh], sa[rb][nb]);
        __builtin_amdgcn_s_setprio(0);

        const bool diag = (kt == nkt - 1);   // only last tile has masked entries
#pragma unroll
        for (int rb = 0; rb < 2; ++rb)
#pragma unroll
            for (int nb = 0; nb < 4; ++nb)
#pragma unroll
                for (int r = 0; r < 4; ++r) {
                    float v = sa[rb][nb][r] * SC;
                    if (diag && (kt * 64 + nb * 16 + c > qrow0 + rb * 16 + 4 * g + r))
                        v = -3e38f;
                    sa[rb][nb][r] = v;
                }

        // ---- online softmax (rows live in 16-lane groups) ----
#pragma unroll
        for (int rb = 0; rb < 2; ++rb) {
            float corr[4];
#pragma unroll
            for (int r = 0; r < 4; ++r) {
                float m0 = fmaxf(fmaxf(sa[rb][0][r], sa[rb][1][r]),
                                 fmaxf(sa[rb][2][r], sa[rb][3][r]));
                m0 = fmaxf(m0, __shfl_xor(m0, 1));
                m0 = fmaxf(m0, __shfl_xor(m0, 2));
                m0 = fmaxf(m0, __shfl_xor(m0, 4));
                m0 = fmaxf(m0, __shfl_xor(m0, 8));
                float mn = fmaxf(m_run[rb][r], m0);
                corr[r] = exp2f(m_run[rb][r] - mn);
                m_run[rb][r] = mn;
            }
#pragma unroll
            for (int nb = 0; nb < 4; ++nb)
#pragma unroll
                for (int r = 0; r < 4; ++r)
                    sa[rb][nb][r] = exp2f(sa[rb][nb][r] - m_run[rb][r]);
#pragma unroll
            for (int r = 0; r < 4; ++r) {
                float s_ = sa[rb][0][r] + sa[rb][1][r] + sa[rb][2][r] + sa[rb][3][r];
                s_ += __shfl_xor(s_, 1); s_ += __shfl_xor(s_, 2);
                s_ += __shfl_xor(s_, 4); s_ += __shfl_xor(s_, 8);
                l_run[rb][r] = l_run[rb][r] * corr[r] + s_;
            }
            float4v cv; cv[0] = corr[0]; cv[1] = corr[1]; cv[2] = corr[2]; cv[3] = corr[3];
#pragma unroll
            for (int nb = 0; nb < 4; ++nb) o[rb][nb] *= cv;
            // P -> bf16 -> LDS (lane transpose); same-wave DS ordering, no barrier
#pragma unroll
            for (int nb = 0; nb < 4; ++nb)
#pragma unroll
                for (int r = 0; r < 4; ++r)
                    Pl[rb][4 * g + r][nb * 16 + c] = f2bf(sa[rb][nb][r]);
        }

        // ---- O += P V ----
        short8v pa[2][2];
#pragma unroll
        for (int rb = 0; rb < 2; ++rb)
#pragma unroll
            for (int kh = 0; kh < 2; ++kh)
                pa[rb][kh] = *(const short8v*)&Pl[rb][c][kh * 32 + g * 8];
        short8v vf[4][2];
#pragma unroll
        for (int nb = 0; nb < 4; ++nb)
#pragma unroll
            for (int kh = 0; kh < 2; ++kh)
                vf[nb][kh] = *(const short8v*)(Vt + vbase +
                                 (size_t)(nb * 16 + c) * SS + kt * 64 + kh * 32 + g * 8);
        __builtin_amdgcn_s_setprio(1);
#pragma unroll
        for (int nb = 0; nb < 4; ++nb)
#pragma unroll
            for (int kh = 0; kh < 2; ++kh)
#pragma unroll
                for (int rb = 0; rb < 2; ++rb)
                    o[rb][nb] = MFMA16(pa[rb][kh], vf[nb][kh], o[rb][nb]);
        __builtin_amdgcn_s_setprio(0);
    }

    // epilogue: store unnormalized O + (m, l)
#pragma unroll
    for (int rb = 0; rb < 2; ++rb)
#pragma unroll
        for (int nb = 0; nb < 4; ++nb)
#pragma unroll
            for (int r = 0; r < 4; ++r)
                myo[(rb * 16 + 4 * g + r) * 64 + nb * 16 + c] = o[rb][nb][r];
    if (c == 0)
#pragma unroll
        for (int rb = 0; rb < 2; ++rb)
#pragma unroll
            for (int r = 0; r < 4; ++r) {
                mym[rb * 16 + 4 * g + r] = m_run[rb][r];
                mym[32 + rb * 16 + 4 * g + r] = l_run[rb][r];
            }
}

// ---------------------------------------------------------------------------
// Combine split partials: out = (e0*o0 + e1*o1) / (e0*l0 + e1*l1), bf16.
// ---------------------------------------------------------------------------
__global__ __launch_bounds__(256) void attn_comb(const float* __restrict__ po,
                                                 const float* __restrict__ pml,
                                                 u16* __restrict__ Ao) {
    const int uid = blockIdx.x;
    const int bh = uid & 31;
    const int u = 63 - (uid >> 5);
    const int b = bh >> 4, h = bh & 15;
    const int qrow0 = u * 32;
    const int t = threadIdx.x;
    const int row = t >> 3, c8 = (t & 7) * 8;

    const float* ml0 = pml + (size_t)(uid * 2 + 0) * 64;
    const float* ml1 = pml + (size_t)(uid * 2 + 1) * 64;
    const float m0 = ml0[row], l0 = ml0[32 + row];
    const float m1 = ml1[row], l1 = ml1[32 + row];
    const float mm = fmaxf(m0, m1);
    const float e0 = exp2f(m0 - mm), e1 = exp2f(m1 - mm);
    const float inv = 1.0f / (e0 * l0 + e1 * l1);

    const float* o0 = po + ((size_t)(uid * 2 + 0) * 32 + row) * 64 + c8;
    const float* o1 = po + ((size_t)(uid * 2 + 1) * 32 + row) * 64 + c8;
    float4 a0 = *(const float4*)o0, b0 = *(const float4*)(o0 + 4);
    float4 a1 = *(const float4*)o1, b1 = *(const float4*)(o1 + 4);
    ushort8v ov;
    ov[0] = f2bf((e0 * a0.x + e1 * a1.x) * inv);
    ov[1] = f2bf((e0 * a0.y + e1 * a1.y) * inv);
    ov[2] = f2bf((e0 * a0.z + e1 * a1.z) * inv);
    ov[3] = f2bf((e0 * a0.w + e1 * a1.w) * inv);
    ov[4] = f2bf((e0 * b0.x + e1 * b1.x) * inv);
    ov[5] = f2bf((e0 * b0.y + e1 * b1.y) * inv);
    ov[6] = f2bf((e0 * b0.z + e1 * b1.z) * inv);
    ov[7] = f2bf((e0 * b0.w + e1 * b1.w) * inv);
    *(ushort8v*)(Ao + (size_t)b * SS * DD + (size_t)(qrow0 + row) * DD + h * 64 + c8) = ov;
}

// ---------------------------------------------------------------------------
// launch: h = x + attn(srmsnorm(x)); out = h + gelu(srmsnorm(h)@w_in)@w_out
// ws layout (MB): 0 wq_t|2 wk_t|4 wv_t (fused [3072][1024]) | 6 wo_t | 8 wi_t
//  | 16 wo2_t | 24 xn (reused: pml) | 32 qb|kb|vb (reused: w_out split-K
//  partials p0/p1, 32MB) | 56 vt | 64 ao | 72 hn | 80 gbuf(32MB, also attn po
//  partials — temporally disjoint). Total 112 MB.
// ---------------------------------------------------------------------------
extern "C" void kernel_launch(void* const* d_in, const int* in_sizes, int n_in,
                              void* d_out, int out_size, void* d_ws, size_t ws_size,
                              hipStream_t stream) {
    const float* x     = (const float*)d_in[0];
    const float* wq    = (const float*)d_in[1];
    const float* wk    = (const float*)d_in[2];
    const float* wv    = (const float*)d_in[3];
    const float* wo    = (const float*)d_in[4];
    const float* w_in  = (const float*)d_in[5];
    const float* w_out = (const float*)d_in[6];
    float* out = (float*)d_out;
    char* ws = (char*)d_ws;
    const size_t MB = 1024 * 1024;
    u16* wq_t  = (u16*)(ws + 0 * MB);   // [3072][1024] fused (wq|wk|wv)
    u16* wo_t  = (u16*)(ws + 6 * MB);
    u16* wi_t  = (u16*)(ws + 8 * MB);
    u16* wo2_t = (u16*)(ws + 16 * MB);
    u16* xn    = (u16*)(ws + 24 * MB);
    u16* qb    = (u16*)(ws + 32 * MB);  // q|k|v contiguous [3][4096][1024]
    u16* vb    = (u16*)(ws + 48 * MB);
    u16* vt    = (u16*)(ws + 56 * MB);
    u16* ao    = (u16*)(ws + 64 * MB);
    u16* hn    = (u16*)(ws + 72 * MB);
    u16* gbuf  = (u16*)(ws + 80 * MB);
    float* po  = (float*)(ws + 80 * MB);   // 32MB partial O (dead before gbuf)
    float* pml = (float*)(ws + 24 * MB);   // 1MB partial (m,l); xn dead by then
    float* psum = (float*)(ws + 32 * MB);  // 32MB w_out split-K partials
                                           // (qb/kb/vb+vt dead after attn)

    dim3 blk(256);
    // all weights -> bf16 transposed [N][K], single launch
    wtrans_all<<<dim3(3072), blk, 0, stream>>>(wq, wk, wv, wo, w_in, w_out, ws);

    srmsnorm_bf16<<<MM, blk, 0, stream>>>(x, xn);
    // fused QKV: N=3072, epilogue scatters into qb/kb/vb
    gemm_bf16<128, 128, 3><<<dim3(3072 / 128, MM / 128), blk, 0, stream>>>(
        xn, wq_t, nullptr, qb, MM, 3072, DD);
    vtrans<<<dim3(SS / 64, BB * HH), blk, 0, stream>>>(vb, vt);
    attn_split<<<dim3(32 * 64 * 2), dim3(64), 0, stream>>>(
        qb, qb + (size_t)MM * 1024, vt, po, pml);
    attn_comb<<<dim3(2048), blk, 0, stream>>>(po, pml, ao);
    gemm_bf16<128, 128, 1><<<dim3(DD / 128, MM / 128), blk, 0, stream>>>(ao, wo_t, x, out, MM, DD, DD); // h
    srmsnorm_bf16<<<MM, blk, 0, stream>>>(out, hn);
    gemm_bf16<128, 128, 2><<<dim3(FF / 128, MM / 128), blk, 0, stream>>>(hn, wi_t, nullptr, gbuf, MM, FF, DD);
    // w_out: split-K x2 (512 blocks -> 2/CU), f32 partials, then combine
    gemm_bf16<128, 128, 4><<<dim3(DD / 128, MM / 128, 2), blk, 0, stream>>>(
        gbuf, wo2_t, nullptr, psum, MM, DD, FF);
    add2_f32<<<dim3(4096), blk, 0, stream>>>(psum, psum + (size_t)MM * DD, out); // out = h + ff
}